// Round 1
// baseline (4219.468 us; speedup 1.0000x reference)
//
#include <hip/hip_runtime.h>
#include <hip/hip_bf16.h>
#include <math.h>

// Problem constants (reference: VOCAB=10000, HID=256, B=64, T=64)
#define VOCABN 10000
#define HIDN   256
#define GATES  1024   // 4*HID
#define BN     64
#define TN     64
#define BT     4096   // B*T
#define RT     16     // rows per block for the two big GEMM-ish kernels

__device__ __forceinline__ float fast_sigmoid(float x) {
    return 1.0f / (1.0f + __expf(-x));
}
__device__ __forceinline__ float fast_tanh(float x) {
    float e = __expf(-2.0f * fabsf(x));
    float t = (1.0f - e) / (1.0f + e);
    return copysignf(t, x);
}

// ---------------------------------------------------------------------------
// Kernel 1: gates_x[(b,t), j] = sum_k E[idx[b,t], k] * W_lstm[k, j] + b_lstm[j]
// Grid: 256 blocks (16 rows each) x 256 threads. Thread handles cols
// {tid, tid+256, tid+512, tid+768} so the 4 gate streams stay coalesced.
// ---------------------------------------------------------------------------
__global__ __launch_bounds__(256) void k_xgates(
    const int*   __restrict__ idx,   // [BT]
    const float* __restrict__ E,     // [VOCAB][HID]
    const float* __restrict__ W,     // [2*HID][GATES] (x-part rows 0..255)
    const float* __restrict__ bl,    // [GATES]
    float*       __restrict__ gx)    // [BT][GATES]
{
    __shared__ float xs[RT][HIDN];   // 16 KB
    const int r0  = blockIdx.x * RT;
    const int tid = threadIdx.x;

    #pragma unroll
    for (int i = 0; i < RT; ++i) {
        int id = idx[r0 + i];                 // uniform -> scalar load
        xs[i][tid] = E[(size_t)id * HIDN + tid];
    }
    __syncthreads();

    float acc[RT][4];
    const float b0 = bl[tid], b1 = bl[tid + 256], b2 = bl[tid + 512], b3 = bl[tid + 768];
    #pragma unroll
    for (int i = 0; i < RT; ++i) {
        acc[i][0] = b0; acc[i][1] = b1; acc[i][2] = b2; acc[i][3] = b3;
    }

    #pragma unroll 4
    for (int k = 0; k < HIDN; ++k) {
        const float* wr = W + (size_t)k * GATES;
        float w0 = wr[tid];
        float w1 = wr[tid + 256];
        float w2 = wr[tid + 512];
        float w3 = wr[tid + 768];
        #pragma unroll
        for (int i = 0; i < RT; ++i) {
            float xv = xs[i][k];              // LDS broadcast (free)
            acc[i][0] = fmaf(xv, w0, acc[i][0]);
            acc[i][1] = fmaf(xv, w1, acc[i][1]);
            acc[i][2] = fmaf(xv, w2, acc[i][2]);
            acc[i][3] = fmaf(xv, w3, acc[i][3]);
        }
    }

    #pragma unroll
    for (int i = 0; i < RT; ++i) {
        float* o = gx + (size_t)(r0 + i) * GATES;
        o[tid]       = acc[i][0];
        o[tid + 256] = acc[i][1];
        o[tid + 512] = acc[i][2];
        o[tid + 768] = acc[i][3];
    }
}

// ---------------------------------------------------------------------------
// Kernel 2: LSTM recurrence. One block per batch row b (sequences are
// independent -> no grid sync). Thread j owns hidden unit j: it computes gate
// columns j (i), j+256 (cell), j+512 (f), j+768 (o), then c/h update locally.
// h broadcast through LDS; c lives in a register.
// ---------------------------------------------------------------------------
__global__ __launch_bounds__(256) void k_lstm(
    const float* __restrict__ W,    // [2*HID][GATES]; h-part rows 256..511
    const float* __restrict__ gx,   // [BT][GATES]
    float*       __restrict__ H)    // [BT][HID]  (row r = b*TN + t)
{
    __shared__ float hs[HIDN];
    const int b = blockIdx.x;
    const int j = threadIdx.x;
    const float* Wh = W + (size_t)HIDN * GATES;   // rows 256..511

    float c = 0.0f;
    hs[j] = 0.0f;
    __syncthreads();

    for (int t = 0; t < TN; ++t) {
        const float* g = gx + ((size_t)b * TN + t) * GATES;
        float ai = g[j];
        float aj = g[j + 256];
        float af = g[j + 512];
        float ao = g[j + 768];

        #pragma unroll 4
        for (int k = 0; k < HIDN; ++k) {
            float hk = hs[k];                 // LDS broadcast
            const float* wr = Wh + (size_t)k * GATES;
            ai = fmaf(hk, wr[j],       ai);
            aj = fmaf(hk, wr[j + 256], aj);
            af = fmaf(hk, wr[j + 512], af);
            ao = fmaf(hk, wr[j + 768], ao);
        }

        float ig = fast_sigmoid(ai);
        float fg = fast_sigmoid(af + 1.0f);   // forget_bias = 1.0
        float og = fast_sigmoid(ao);
        float jt = fast_tanh(aj);
        c = fg * c + ig * jt;
        float hn = og * fast_tanh(c);

        __syncthreads();                      // all readers of hs done
        hs[j] = hn;
        H[((size_t)b * TN + t) * HIDN + j] = hn;
        __syncthreads();                      // hs visible for next step
    }
}

// ---------------------------------------------------------------------------
// Kernel 3: logits = H @ W_dense + b_dense, online log-softmax, gather target,
// ppl = exp(lse - logit_target). Never materializes logits.
// Grid: 256 blocks (16 rows each) x 256 threads; each thread streams vocab
// columns v = tid, tid+256, ... with a running (max, sumexp) per row.
// ---------------------------------------------------------------------------
__global__ __launch_bounds__(256) void k_dense(
    const float* __restrict__ H,     // [BT][HID]
    const float* __restrict__ Wd,    // [HID][VOCAB]
    const float* __restrict__ bd,    // [VOCAB]
    const int*   __restrict__ tgt,   // [BT]
    float*       __restrict__ out)   // [BT]
{
    __shared__ float hsm[RT][HIDN];     // 16 KB
    __shared__ float redm[RT][256];     // 16 KB
    __shared__ float reds[RT][256];     // 16 KB
    __shared__ float tl[RT];
    __shared__ int   tg[RT];

    const int r0  = blockIdx.x * RT;
    const int tid = threadIdx.x;

    #pragma unroll
    for (int i = 0; i < RT; ++i)
        hsm[i][tid] = H[(size_t)(r0 + i) * HIDN + tid];
    if (tid < RT) tg[tid] = tgt[r0 + tid];
    __syncthreads();

    float m[RT], s[RT];
    #pragma unroll
    for (int i = 0; i < RT; ++i) { m[i] = -1e30f; s[i] = 0.0f; }

    for (int v = tid; v < VOCABN; v += 256) {
        float acc[RT];
        float bv = bd[v];
        #pragma unroll
        for (int i = 0; i < RT; ++i) acc[i] = bv;

        #pragma unroll 4
        for (int k = 0; k < HIDN; ++k) {
            float w = Wd[(size_t)k * VOCABN + v];   // coalesced across threads
            #pragma unroll
            for (int i = 0; i < RT; ++i)
                acc[i] = fmaf(hsm[i][k], w, acc[i]);
        }

        #pragma unroll
        for (int i = 0; i < RT; ++i) {
            float l = acc[i];
            if (v == tg[i]) tl[i] = l;              // exactly one writer per row
            float mn = fmaxf(m[i], l);
            s[i] = s[i] * __expf(m[i] - mn) + __expf(l - mn);
            m[i] = mn;
        }
    }

    #pragma unroll
    for (int i = 0; i < RT; ++i) { redm[i][tid] = m[i]; reds[i][tid] = s[i]; }
    __syncthreads();

    if (tid < RT) {
        float mm = -1e30f, ss = 0.0f;
        for (int u = 0; u < 256; ++u) {
            float mu = redm[tid][u], su = reds[tid][u];
            float mn = fmaxf(mm, mu);
            ss = ss * __expf(mm - mn) + su * __expf(mu - mn);
            mm = mn;
        }
        float lse = mm + __logf(ss);
        out[r0 + tid] = __expf(lse - tl[tid]);      // perplexity per token
    }
}

// ---------------------------------------------------------------------------
extern "C" void kernel_launch(void* const* d_in, const int* in_sizes, int n_in,
                              void* d_out, int out_size, void* d_ws, size_t ws_size,
                              hipStream_t stream) {
    const int*   input   = (const int*)  d_in[0];   // [B,T]
    const int*   targets = (const int*)  d_in[1];   // [B,T]
    const float* E       = (const float*)d_in[2];   // [VOCAB,HID]
    const float* W_lstm  = (const float*)d_in[3];   // [2H,4H]
    const float* b_lstm  = (const float*)d_in[4];   // [4H]
    const float* W_dense = (const float*)d_in[5];   // [HID,VOCAB]
    const float* b_dense = (const float*)d_in[6];   // [VOCAB]
    float* out = (float*)d_out;                     // [B,T] perplexity

    // Workspace layout: gates_x [BT][GATES] fp32 (16 MB), H [BT][HID] fp32 (4 MB)
    float* gx = (float*)d_ws;
    float* H  = (float*)((char*)d_ws + (size_t)BT * GATES * sizeof(float));

    k_xgates<<<BT / RT, 256, 0, stream>>>(input, E, W_lstm, b_lstm, gx);
    k_lstm  <<<BN,      256, 0, stream>>>(W_lstm, gx, H);
    k_dense <<<BT / RT, 256, 0, stream>>>(H, W_dense, b_dense, targets, out);
}

// Round 2
// 1246.895 us; speedup vs baseline: 3.3840x; 3.3840x over previous
//
#include <hip/hip_runtime.h>
#include <hip/hip_bf16.h>
#include <math.h>

// Problem constants (reference: VOCAB=10000, HID=256, B=64, T=64)
#define VOCABN 10000
#define HIDN   256
#define GATES  1024   // 4*HID
#define BN     64
#define TN     64
#define BT     4096   // B*T
#define RT     16     // rows per block for the GEMM-ish kernels

__device__ __forceinline__ float fast_sigmoid(float x) {
    return 1.0f / (1.0f + __expf(-x));
}
__device__ __forceinline__ float fast_tanh(float x) {
    float e = __expf(-2.0f * fabsf(x));
    float t = (1.0f - e) / (1.0f + e);
    return copysignf(t, x);
}

// ---------------------------------------------------------------------------
// Kernel 1: gates_x[(b,t), j] = sum_k E[idx[b,t], k] * W_lstm[k, j] + b_lstm[j]
// ---------------------------------------------------------------------------
__global__ __launch_bounds__(256) void k_xgates(
    const int*   __restrict__ idx,   // [BT]
    const float* __restrict__ E,     // [VOCAB][HID]
    const float* __restrict__ W,     // [2*HID][GATES] (x-part rows 0..255)
    const float* __restrict__ bl,    // [GATES]
    float*       __restrict__ gx)    // [BT][GATES]
{
    __shared__ float xs[RT][HIDN];   // 16 KB
    const int r0  = blockIdx.x * RT;
    const int tid = threadIdx.x;

    #pragma unroll
    for (int i = 0; i < RT; ++i) {
        int id = idx[r0 + i];
        xs[i][tid] = E[(size_t)id * HIDN + tid];
    }
    __syncthreads();

    float acc[RT][4];
    const float b0 = bl[tid], b1 = bl[tid + 256], b2 = bl[tid + 512], b3 = bl[tid + 768];
    #pragma unroll
    for (int i = 0; i < RT; ++i) {
        acc[i][0] = b0; acc[i][1] = b1; acc[i][2] = b2; acc[i][3] = b3;
    }

    #pragma unroll 4
    for (int k = 0; k < HIDN; ++k) {
        const float* wr = W + (size_t)k * GATES;
        float w0 = wr[tid];
        float w1 = wr[tid + 256];
        float w2 = wr[tid + 512];
        float w3 = wr[tid + 768];
        #pragma unroll
        for (int i = 0; i < RT; ++i) {
            float xv = xs[i][k];
            acc[i][0] = fmaf(xv, w0, acc[i][0]);
            acc[i][1] = fmaf(xv, w1, acc[i][1]);
            acc[i][2] = fmaf(xv, w2, acc[i][2]);
            acc[i][3] = fmaf(xv, w3, acc[i][3]);
        }
    }

    #pragma unroll
    for (int i = 0; i < RT; ++i) {
        float* o = gx + (size_t)(r0 + i) * GATES;
        o[tid]       = acc[i][0];
        o[tid + 256] = acc[i][1];
        o[tid + 512] = acc[i][2];
        o[tid + 768] = acc[i][3];
    }
}

// ---------------------------------------------------------------------------
// Kernel 2: LSTM recurrence. One block per batch row, 1024 threads (16 waves
// per CU for latency hiding). Thread tid owns gate column tid: per step it
// does a 256-long dot of h (LDS, float4 broadcast reads) with W_h column tid
// (global, coalesced 4B/lane). Gate pre-acts exchanged via LDS; threads <256
// apply the cell update and publish the new h.
// ---------------------------------------------------------------------------
__global__ __launch_bounds__(1024) void k_lstm(
    const float* __restrict__ W,    // [2*HID][GATES]; h-part rows 256..511
    const float* __restrict__ gx,   // [BT][GATES]
    float*       __restrict__ H)    // [BT][HID]
{
    __shared__ float hs[HIDN];      // current hidden state (broadcast source)
    __shared__ float gact[GATES];   // gate pre-activation exchange
    const int b   = blockIdx.x;
    const int tid = threadIdx.x;
    const float* Wh = W + (size_t)HIDN * GATES;   // rows 256..511

    float cstate = 0.0f;            // valid for tid < 256
    if (tid < HIDN) hs[tid] = 0.0f;
    __syncthreads();

    for (int t = 0; t < TN; ++t) {
        float a = gx[((size_t)b * TN + t) * GATES + tid];

        const float4* hs4 = (const float4*)hs;
        #pragma unroll 8
        for (int k4 = 0; k4 < HIDN / 4; ++k4) {
            float4 h4 = hs4[k4];                       // LDS b128 broadcast
            const float* wr = Wh + (size_t)(k4 * 4) * GATES + tid;
            a = fmaf(h4.x, wr[0],         a);
            a = fmaf(h4.y, wr[GATES],     a);
            a = fmaf(h4.z, wr[2 * GATES], a);
            a = fmaf(h4.w, wr[3 * GATES], a);
        }
        gact[tid] = a;
        __syncthreads();             // all hs reads + gact writes done

        if (tid < HIDN) {
            float ai = gact[tid];
            float aj = gact[tid + 256];
            float af = gact[tid + 512];
            float ao = gact[tid + 768];
            float ig = fast_sigmoid(ai);
            float fg = fast_sigmoid(af + 1.0f);        // forget_bias = 1.0
            float og = fast_sigmoid(ao);
            float jt = fast_tanh(aj);
            cstate = fg * cstate + ig * jt;
            float hn = og * fast_tanh(cstate);
            hs[tid] = hn;
            H[((size_t)b * TN + t) * HIDN + tid] = hn;
        }
        __syncthreads();             // hs visible before next step's reads
    }
}

// ---------------------------------------------------------------------------
// Kernel 3: dense + online log-softmax + target gather, never materializing
// logits. 256 blocks x 256 threads, 16 rows/block. Vocab walked in chunks of
// 1024 cols: thread owns 4 consecutive cols (float4 W loads -> 64 FMA/load).
// 10000 = 9*1024 + 784; tail chunk uses threads 0..195 (784 = 196*4 exactly).
// ---------------------------------------------------------------------------
__global__ __launch_bounds__(256) void k_dense(
    const float* __restrict__ H,     // [BT][HID]
    const float* __restrict__ Wd,    // [HID][VOCAB]
    const float* __restrict__ bd,    // [VOCAB]
    const int*   __restrict__ tgt,   // [BT]
    float*       __restrict__ out)   // [BT]
{
    __shared__ float hsm[RT][HIDN];     // 16 KB
    __shared__ float redm[RT][256];     // 16 KB
    __shared__ float reds[RT][256];     // 16 KB
    __shared__ float tl[RT];
    __shared__ int   tg[RT];

    const int r0  = blockIdx.x * RT;
    const int tid = threadIdx.x;

    {   // vectorized load of the 16 h rows (4096 floats = 1024 float4)
        const float4* src = (const float4*)(H + (size_t)r0 * HIDN);
        float4* dst = (float4*)hsm;
        #pragma unroll
        for (int j = 0; j < 4; ++j)
            dst[tid + 256 * j] = src[tid + 256 * j];
    }
    if (tid < RT) tg[tid] = tgt[r0 + tid];
    __syncthreads();

    float m[RT], s[RT];
    #pragma unroll
    for (int i = 0; i < RT; ++i) { m[i] = -1e30f; s[i] = 0.0f; }

    for (int chunk = 0; chunk < 10; ++chunk) {
        const int v0 = chunk * 1024 + tid * 4;
        if (v0 >= VOCABN) break;                       // tail: threads >=196 idle

        float4 acc[RT];
        {
            float4 bv = *(const float4*)(bd + v0);
            #pragma unroll
            for (int i = 0; i < RT; ++i) acc[i] = bv;
        }

        #pragma unroll 2
        for (int k = 0; k < HIDN; k += 4) {
            const float* wp = Wd + (size_t)k * VOCABN + v0;
            float4 w0 = *(const float4*)(wp);
            float4 w1 = *(const float4*)(wp + VOCABN);
            float4 w2 = *(const float4*)(wp + 2 * VOCABN);
            float4 w3 = *(const float4*)(wp + 3 * VOCABN);
            #pragma unroll
            for (int i = 0; i < RT; ++i) {
                float4 h4 = *(const float4*)&hsm[i][k];  // LDS b128 broadcast
                acc[i].x = fmaf(h4.x, w0.x, acc[i].x);
                acc[i].y = fmaf(h4.x, w0.y, acc[i].y);
                acc[i].z = fmaf(h4.x, w0.z, acc[i].z);
                acc[i].w = fmaf(h4.x, w0.w, acc[i].w);
                acc[i].x = fmaf(h4.y, w1.x, acc[i].x);
                acc[i].y = fmaf(h4.y, w1.y, acc[i].y);
                acc[i].z = fmaf(h4.y, w1.z, acc[i].z);
                acc[i].w = fmaf(h4.y, w1.w, acc[i].w);
                acc[i].x = fmaf(h4.z, w2.x, acc[i].x);
                acc[i].y = fmaf(h4.z, w2.y, acc[i].y);
                acc[i].z = fmaf(h4.z, w2.z, acc[i].z);
                acc[i].w = fmaf(h4.z, w2.w, acc[i].w);
                acc[i].x = fmaf(h4.w, w3.x, acc[i].x);
                acc[i].y = fmaf(h4.w, w3.y, acc[i].y);
                acc[i].z = fmaf(h4.w, w3.z, acc[i].z);
                acc[i].w = fmaf(h4.w, w3.w, acc[i].w);
            }
        }

        #pragma unroll
        for (int i = 0; i < RT; ++i) {
            // target capture (exactly one writer per row across grid-block)
            int d = tg[i] - v0;
            if ((unsigned)d < 4u) {
                float lt = (d == 0) ? acc[i].x : (d == 1) ? acc[i].y
                         : (d == 2) ? acc[i].z : acc[i].w;
                tl[i] = lt;
            }
            // online (max, sumexp) update with the 4 new logits
            float mloc = fmaxf(fmaxf(acc[i].x, acc[i].y), fmaxf(acc[i].z, acc[i].w));
            float mn = fmaxf(m[i], mloc);
            float add = __expf(acc[i].x - mn) + __expf(acc[i].y - mn)
                      + __expf(acc[i].z - mn) + __expf(acc[i].w - mn);
            s[i] = s[i] * __expf(m[i] - mn) + add;
            m[i] = mn;
        }
    }

    #pragma unroll
    for (int i = 0; i < RT; ++i) { redm[i][tid] = m[i]; reds[i][tid] = s[i]; }
    __syncthreads();

    if (tid < RT) {
        float mm = -1e30f, ss = 0.0f;
        for (int u = 0; u < 256; ++u) {
            float mu = redm[tid][u], su = reds[tid][u];
            float mn = fmaxf(mm, mu);
            ss = ss * __expf(mm - mn) + su * __expf(mu - mn);
            mm = mn;
        }
        float lse = mm + __logf(ss);
        out[r0 + tid] = __expf(lse - tl[tid]);      // perplexity per token
    }
}

// ---------------------------------------------------------------------------
extern "C" void kernel_launch(void* const* d_in, const int* in_sizes, int n_in,
                              void* d_out, int out_size, void* d_ws, size_t ws_size,
                              hipStream_t stream) {
    const int*   input   = (const int*)  d_in[0];   // [B,T]
    const int*   targets = (const int*)  d_in[1];   // [B,T]
    const float* E       = (const float*)d_in[2];   // [VOCAB,HID]
    const float* W_lstm  = (const float*)d_in[3];   // [2H,4H]
    const float* b_lstm  = (const float*)d_in[4];   // [4H]
    const float* W_dense = (const float*)d_in[5];   // [HID,VOCAB]
    const float* b_dense = (const float*)d_in[6];   // [VOCAB]
    float* out = (float*)d_out;                     // [B,T] perplexity

    // Workspace layout: gates_x [BT][GATES] fp32 (16 MB), H [BT][HID] fp32 (4 MB)
    float* gx = (float*)d_ws;
    float* H  = (float*)((char*)d_ws + (size_t)BT * GATES * sizeof(float));

    k_xgates<<<BT / RT, 256,  0, stream>>>(input, E, W_lstm, b_lstm, gx);
    k_lstm  <<<BN,      1024, 0, stream>>>(W_lstm, gx, H);
    k_dense <<<BT / RT, 256,  0, stream>>>(H, W_dense, b_dense, targets, out);
}

// Round 3
// 762.881 us; speedup vs baseline: 5.5310x; 1.6345x over previous
//
#include <hip/hip_runtime.h>
#include <math.h>

// Problem constants (reference: VOCAB=10000, HID=256, B=64, T=64)
#define VOCABN 10000
#define HIDN   256
#define GATES  1024   // 4*HID
#define BN     64
#define TN     64
#define BT     4096   // B*T
#define NCT    625    // vocab col-tiles of 16 (10000 = 625*16 exactly)

typedef unsigned int   u32;
typedef unsigned short u16;
typedef float v4f __attribute__((ext_vector_type(4)));
typedef short v8s __attribute__((ext_vector_type(8)));

__device__ __forceinline__ float bf2f(u16 u) {
    return __uint_as_float(((u32)u) << 16);
}
__device__ __forceinline__ u16 f2bf(float f) {          // round-to-nearest-even
    u32 u = __float_as_uint(f);
    u += 0x7FFFu + ((u >> 16) & 1u);
    return (u16)(u >> 16);
}
__device__ __forceinline__ float fast_sigmoid(float x) {
    return 1.0f / (1.0f + __expf(-x));
}
__device__ __forceinline__ float fast_tanh(float x) {
    float e = __expf(-2.0f * fabsf(x));
    float t = (1.0f - e) / (1.0f + e);
    return copysignf(t, x);
}

// ---------------------------------------------------------------------------
// Generic fp32 [HIDN][ncols] -> bf16 MFMA B-fragment layout [ct][8 q][64 l][8].
// Fragment (c,q), lane l holds B[k = q*32 + (l>>4)*8 + j][n = c*16 + (l&15)],
// j=0..7, as 16 contiguous bytes -> b_frag load is a single coalesced b128.
// ---------------------------------------------------------------------------
__global__ __launch_bounds__(256) void k_wfrag(
    const float* __restrict__ src,   // [HIDN][ncols]
    u16*         __restrict__ dst,   // [nct][8][64][8]
    int ncols)
{
    __shared__ u16 lt[HIDN][16];
    const int c = blockIdx.x;
    const int t = threadIdx.x;
    const float* s = src + (size_t)t * ncols + c * 16;
    #pragma unroll
    for (int j4 = 0; j4 < 4; ++j4) {
        float4 v = *(const float4*)(s + j4 * 4);
        lt[t][j4*4+0] = f2bf(v.x);
        lt[t][j4*4+1] = f2bf(v.y);
        lt[t][j4*4+2] = f2bf(v.z);
        lt[t][j4*4+3] = f2bf(v.w);
    }
    __syncthreads();
    #pragma unroll
    for (int h = 0; h < 2; ++h) {
        int f = t + h * 256;             // frag id = q*64 + l
        int q = f >> 6, l = f & 63;
        int m = l & 15, kb = q * 32 + ((l >> 4) & 3) * 8;
        u32 w[4];
        #pragma unroll
        for (int j = 0; j < 4; ++j)
            w[j] = (u32)lt[kb + 2*j][m] | ((u32)lt[kb + 2*j + 1][m] << 16);
        *(uint4*)(dst + (((size_t)c * 8 + q) * 64 + l) * 8) =
            make_uint4(w[0], w[1], w[2], w[3]);
    }
}

// ---------------------------------------------------------------------------
// W_lstm h-part [256][1024] fp32 -> plain bf16 [256][1024] (halves L2 stream)
// ---------------------------------------------------------------------------
__global__ __launch_bounds__(256) void k_cvt_wh(
    const float* __restrict__ W,     // W_lstm base; h-part at +HIDN*GATES
    u16*         __restrict__ Whb)
{
    int i = (blockIdx.x * 256 + threadIdx.x) * 4;
    float4 v = *(const float4*)(W + (size_t)HIDN * GATES + i);
    u32 a = (u32)f2bf(v.x) | ((u32)f2bf(v.y) << 16);
    u32 b = (u32)f2bf(v.z) | ((u32)f2bf(v.w) << 16);
    *(uint2*)(Whb + i) = make_uint2(a, b);
}

// ---------------------------------------------------------------------------
// Kernel 1 (MFMA): gates_x = E[idx] @ W_x + b_lstm. 256 blocks x 16 rows.
// A-frags built in-kernel from fp32 E rows (gather by token id).
// ---------------------------------------------------------------------------
__global__ __launch_bounds__(256) void k_xgates(
    const int*   __restrict__ idx,   // [BT]
    const float* __restrict__ E,     // [VOCAB][HIDN]
    const u16*   __restrict__ Wxf,   // [64][8][64][8]
    const float* __restrict__ bl,    // [GATES]
    float*       __restrict__ gx)    // [BT][GATES]
{
    const int r0   = blockIdx.x * 16;
    const int tid  = threadIdx.x;
    const int w    = tid >> 6, lane = tid & 63;
    const int m    = lane & 15, quad = lane >> 4;

    v8s a[8];
    {
        const float* e = E + (size_t)idx[r0 + m] * HIDN + quad * 8;
        #pragma unroll
        for (int q = 0; q < 8; ++q) {
            float4 x0 = *(const float4*)(e + q * 32);
            float4 x1 = *(const float4*)(e + q * 32 + 4);
            uint4 t4 = make_uint4(
                (u32)f2bf(x0.x) | ((u32)f2bf(x0.y) << 16),
                (u32)f2bf(x0.z) | ((u32)f2bf(x0.w) << 16),
                (u32)f2bf(x1.x) | ((u32)f2bf(x1.y) << 16),
                (u32)f2bf(x1.z) | ((u32)f2bf(x1.w) << 16));
            a[q] = *(v8s*)&t4;
        }
    }

    for (int c = w; c < GATES / 16; c += 4) {
        v4f acc = {0.f, 0.f, 0.f, 0.f};
        #pragma unroll
        for (int q = 0; q < 8; ++q) {
            v8s b = *(const v8s*)(Wxf + (((size_t)c * 8 + q) * 64 + lane) * 8);
            acc = __builtin_amdgcn_mfma_f32_16x16x32_bf16(a[q], b, acc, 0, 0, 0);
        }
        const int col = c * 16 + m;
        const float bv = bl[col];
        #pragma unroll
        for (int r = 0; r < 4; ++r)   // D: col=lane&15, row=quad*4+r (m89/m91)
            gx[(size_t)(r0 + quad * 4 + r) * GATES + col] = acc[r] + bv;
    }
}

// ---------------------------------------------------------------------------
// Kernel 2: LSTM recurrence, bf16 weights. One block/batch row, 1024 threads.
// Thread = gate column; h broadcast via LDS float4; writes Hb in bf16.
// ---------------------------------------------------------------------------
__global__ __launch_bounds__(1024) void k_lstm(
    const u16*   __restrict__ Whb,   // [HIDN][GATES] bf16
    const float* __restrict__ gx,    // [BT][GATES]
    u16*         __restrict__ Hb)    // [BT][HIDN] bf16
{
    __shared__ float hs[HIDN];
    __shared__ float gact[GATES];
    const int b   = blockIdx.x;
    const int tid = threadIdx.x;

    float cstate = 0.0f;
    if (tid < HIDN) hs[tid] = 0.0f;
    __syncthreads();

    for (int t = 0; t < TN; ++t) {
        float a = gx[((size_t)b * TN + t) * GATES + tid];
        const float4* hs4 = (const float4*)hs;
        #pragma unroll 8
        for (int k4 = 0; k4 < HIDN / 4; ++k4) {
            float4 h4 = hs4[k4];
            const u16* wr = Whb + (size_t)(k4 * 4) * GATES + tid;
            a = fmaf(h4.x, bf2f(wr[0]),         a);
            a = fmaf(h4.y, bf2f(wr[GATES]),     a);
            a = fmaf(h4.z, bf2f(wr[2 * GATES]), a);
            a = fmaf(h4.w, bf2f(wr[3 * GATES]), a);
        }
        gact[tid] = a;
        __syncthreads();

        if (tid < HIDN) {
            float ai = gact[tid];
            float aj = gact[tid + 256];
            float af = gact[tid + 512];
            float ao = gact[tid + 768];
            float ig = fast_sigmoid(ai);
            float fg = fast_sigmoid(af + 1.0f);       // forget_bias = 1.0
            float og = fast_sigmoid(ao);
            float jt = fast_tanh(aj);
            cstate = fg * cstate + ig * jt;
            float hn = og * fast_tanh(cstate);
            hs[tid] = hn;
            Hb[((size_t)b * TN + t) * HIDN + tid] = f2bf(hn);
        }
        __syncthreads();
    }
}

// ---------------------------------------------------------------------------
// Kernel 3 (MFMA): sum-of-exp over vocab (no running max: |logit| <~ 24 so
// exp never overflows fp32). 256 blocks = 128 row-groups x 2 vocab halves;
// 32 rows/block; a-frags register-resident across the whole vocab sweep.
// ---------------------------------------------------------------------------
__global__ __launch_bounds__(256) void k_dense(
    const u16*   __restrict__ Hb,    // [BT][HIDN] bf16
    const u16*   __restrict__ Wf,    // [625][8][64][8]
    const float* __restrict__ bd,    // [VOCAB]
    float*       __restrict__ S)     // [2][BT] partial sumexp
{
    __shared__ float Sl[32];
    const int rg  = blockIdx.x >> 1, hv = blockIdx.x & 1;
    const int r0  = rg * 32;
    const int tid = threadIdx.x;
    const int w   = tid >> 6, lane = tid & 63;
    const int m   = lane & 15, quad = lane >> 4;

    if (tid < 32) Sl[tid] = 0.0f;

    v8s a[2][8];
    #pragma unroll
    for (int rt = 0; rt < 2; ++rt) {
        const u16* hrow = Hb + (size_t)(r0 + rt * 16 + m) * HIDN + quad * 8;
        #pragma unroll
        for (int q = 0; q < 8; ++q)
            a[rt][q] = *(const v8s*)(hrow + q * 32);
    }
    __syncthreads();

    float s[2][4] = {{0.f,0.f,0.f,0.f},{0.f,0.f,0.f,0.f}};
    const int cbeg = hv ? 313 : 0;
    const int cend = hv ? NCT : 313;
    for (int c = cbeg + w; c < cend; c += 4) {
        v4f acc0 = {0.f,0.f,0.f,0.f};
        v4f acc1 = {0.f,0.f,0.f,0.f};
        #pragma unroll
        for (int q = 0; q < 8; ++q) {
            v8s bq = *(const v8s*)(Wf + (((size_t)c * 8 + q) * 64 + lane) * 8);
            acc0 = __builtin_amdgcn_mfma_f32_16x16x32_bf16(a[0][q], bq, acc0, 0, 0, 0);
            acc1 = __builtin_amdgcn_mfma_f32_16x16x32_bf16(a[1][q], bq, acc1, 0, 0, 0);
        }
        float bv = bd[c * 16 + m];
        #pragma unroll
        for (int r = 0; r < 4; ++r) {
            s[0][r] += __expf(acc0[r] + bv);
            s[1][r] += __expf(acc1[r] + bv);
        }
    }

    #pragma unroll
    for (int rt = 0; rt < 2; ++rt)
        #pragma unroll
        for (int r = 0; r < 4; ++r)
            atomicAdd(&Sl[rt * 16 + quad * 4 + r], s[rt][r]);
    __syncthreads();
    if (tid < 32) S[(size_t)hv * BT + r0 + tid] = Sl[tid];
}

// ---------------------------------------------------------------------------
// Kernel 4: target logit per row (direct dot from bf16 frags). 32 thr/row.
// ---------------------------------------------------------------------------
__global__ __launch_bounds__(256) void k_target(
    const u16*   __restrict__ Hb,
    const u16*   __restrict__ Wf,
    const float* __restrict__ bd,
    const int*   __restrict__ tgt,
    float*       __restrict__ tl)    // [BT]
{
    const int tid = threadIdx.x;
    const int row = blockIdx.x * 8 + (tid >> 5);
    const int t   = tid & 31;
    const int q   = t >> 2, lq = t & 3;
    const int v   = tgt[row];
    const int c   = v >> 4, vm = v & 15;
    const int kb  = q * 32 + lq * 8;

    v8s h  = *(const v8s*)(Hb + (size_t)row * HIDN + kb);
    v8s wv = *(const v8s*)(Wf + (((size_t)c * 8 + q) * 64 + lq * 16 + vm) * 8);
    float acc = 0.0f;
    #pragma unroll
    for (int j = 0; j < 8; ++j)
        acc = fmaf(bf2f((u16)h[j]), bf2f((u16)wv[j]), acc);
    #pragma unroll
    for (int off = 16; off >= 1; off >>= 1)
        acc += __shfl_down(acc, off, 32);
    if (t == 0) tl[row] = acc + bd[v];
}

// ---------------------------------------------------------------------------
// Kernel 5: ppl = exp(log(sumexp) - target_logit)
// ---------------------------------------------------------------------------
__global__ __launch_bounds__(256) void k_final(
    const float* __restrict__ S,     // [2][BT]
    const float* __restrict__ tl,    // [BT]
    float*       __restrict__ out)   // [BT]
{
    int i = blockIdx.x * 256 + threadIdx.x;
    out[i] = __expf(__logf(S[i] + S[BT + i]) - tl[i]);
}

// ---------------------------------------------------------------------------
extern "C" void kernel_launch(void* const* d_in, const int* in_sizes, int n_in,
                              void* d_out, int out_size, void* d_ws, size_t ws_size,
                              hipStream_t stream) {
    const int*   input   = (const int*)  d_in[0];   // [B,T]
    const int*   targets = (const int*)  d_in[1];   // [B,T]
    const float* E       = (const float*)d_in[2];   // [VOCAB,HID]
    const float* W_lstm  = (const float*)d_in[3];   // [2H,4H]
    const float* b_lstm  = (const float*)d_in[4];   // [4H]
    const float* W_dense = (const float*)d_in[5];   // [HID,VOCAB]
    const float* b_dense = (const float*)d_in[6];   // [VOCAB]
    float* out = (float*)d_out;                     // [B,T] perplexity

    // Workspace (~19.05 MB; 20 MB was in use previously so ws_size covers it):
    //  [0,16M):        gx fp32 [BT][GATES]; after k_lstm the same region is
    //                  reused for Wf (5.12 MB) — stream-ordered, no overlap.
    //  [16M,18M):      Hb bf16 [BT][HIDN]
    //  [18M,18.5M):    Whb bf16 [HIDN][GATES]
    //  [18.5M,19M):    Wxf bf16 [64][8][64][8]
    //  [19M,+32K):     S fp32 [2][BT]
    //  [+32K,+48K):    tl fp32 [BT]
    char* ws = (char*)d_ws;
    float* gx  = (float*)ws;
    u16*   Wf  = (u16*)ws;
    u16*   Hb  = (u16*)(ws + ((size_t)16 << 20));
    u16*   Whb = (u16*)(ws + ((size_t)18 << 20));
    u16*   Wxf = (u16*)(ws + ((size_t)18 << 20) + ((size_t)512 << 10));
    float* S   = (float*)(ws + ((size_t)19 << 20));
    float* tl  = (float*)(ws + ((size_t)19 << 20) + ((size_t)32 << 10));

    k_wfrag <<<64,      256,  0, stream>>>(W_lstm,  Wxf, GATES);   // x-part
    k_cvt_wh<<<256,     256,  0, stream>>>(W_lstm,  Whb);          // h-part
    k_xgates<<<BT / 16, 256,  0, stream>>>(input, E, Wxf, b_lstm, gx);
    k_lstm  <<<BN,      1024, 0, stream>>>(Whb, gx, Hb);
    k_wfrag <<<NCT,     256,  0, stream>>>(W_dense, Wf, VOCABN);   // reuses gx region
    k_dense <<<256,     256,  0, stream>>>(Hb, Wf, b_dense, S);
    k_target<<<BT / 8,  256,  0, stream>>>(Hb, Wf, b_dense, targets, tl);
    k_final <<<BT / 256,256,  0, stream>>>(S, tl, out);
}